// Round 6
// baseline (438.036 us; speedup 1.0000x reference)
//
#include <hip/hip_runtime.h>
#include <hip/hip_bf16.h>
#include <stdint.h>

typedef unsigned short u16;
typedef _Float16 f16;
typedef short vs8 __attribute__((ext_vector_type(8)));   // 8 x bf16 bits (MFMA A/B frag)
typedef float vf4 __attribute__((ext_vector_type(4)));   // MFMA C/D frag
typedef _Float16 vh2 __attribute__((ext_vector_type(2)));
typedef _Float16 vh4 __attribute__((ext_vector_type(4)));
typedef _Float16 vh8 __attribute__((ext_vector_type(8)));
typedef __fp16 hw2 __attribute__((ext_vector_type(2)));  // cvt_pkrtz return type

// Problem constants: B=4 T=2048 E=256 H=8 HD=32 FE=4 L=4
//
// R16: XOR-swizzled GEMM LDS tiles (bank-conflict fix): -39 us, confirmed.
// R17: counted-vmcnt 2-phase graft on gemm_ln: +33 us REGRESSION (needs 8-phase regime;
//      added barriers + width-4 staging + sched_barrier pin). Reverted here.
// R18: launch-count attack. Each gemm_ln block emits complete 32x256 LN rows = the full
//      K-contraction input of the next GEMM -> append optional phase-2 GEMM:
//      LN1+ff1 fused (kills 4 ff1 launches + Xb reread), LN2+qkv_next fused (kills 4 qkv
//      launches). LN output bounced via swizzled As2[32][256] LDS tile.

__device__ __forceinline__ void gload16(const u16* g, u16* l) {
  __builtin_amdgcn_global_load_lds((const __attribute__((address_space(1))) void*)g,
                                   (__attribute__((address_space(3))) void*)l,
                                   16, 0, 0);
}

__device__ __forceinline__ float fexp2(float x) {
#if __has_builtin(__builtin_amdgcn_exp2f)
  return __builtin_amdgcn_exp2f(x);
#else
  return __expf(x * 0.69314718056f);
#endif
}

// ---------------- Fourier PE -> bf16 (fast trig: exp2 + hw sin/cos in revolutions) ----------------
__global__ void pe_kernel(const float* __restrict__ x, __hip_bfloat16* __restrict__ Xb) {
  int gid = blockIdx.x * 256 + threadIdx.x;   // 0..524287
  int row = gid >> 6;                          // 0..8191 (64 thr/row, 4 elems each)
  int e0 = (gid & 63) * 4;                     // 0..252, 4-aligned; same side of 128
  int t = row & 2047;
  int f0 = (e0 < 128) ? e0 : (e0 - 128);
  const float c = -13.287712379549449f / 128.0f;   // -log2(10000)/128
  const float inv2pi = 0.15915494309189535f;
  float4 xv = *(const float4*)(x + (size_t)row * 256 + e0);
  u16 o[4];
#pragma unroll
  for (int j = 0; j < 4; ++j) {
    float freq = fexp2(c * (float)(f0 + j));
    float rev = (float)t * freq * inv2pi;
    rev = rev - floorf(rev);
    float pe = (e0 < 128) ? __builtin_amdgcn_sinf(rev) : __builtin_amdgcn_cosf(rev);
    float xin = (j == 0) ? xv.x : (j == 1) ? xv.y : (j == 2) ? xv.z : xv.w;
    __hip_bfloat16 hb = __float2bfloat16(xin + pe);
    o[j] = *(u16*)&hb;
  }
  *(uint2*)((u16*)Xb + (size_t)row * 256 + e0) = *(uint2*)o;
}

// ---------------- merged weight transpose + cast: f32 [L][K][N] -> bf16 [L][N][K] ----------------
__global__ void transpose_cast_all(
    const float* __restrict__ w0, const float* __restrict__ w1,
    const float* __restrict__ w2, const float* __restrict__ w3,
    u16* __restrict__ o0, u16* __restrict__ o1,
    u16* __restrict__ o2, u16* __restrict__ o3) {
  __shared__ float tile[32][33];
  int flat = blockIdx.x;                 // 0..3071
  int layer = flat / 768;
  int r = flat - layer * 768;
  const float* ip; u16* op; int K, N, kt, nt;
  if (r < 192)      {              ip = w0; op = o0; K = 256;  N = 768;  kt = r & 7;  nt = r >> 3; }  // qkv 8x24
  else if (r < 256) { int q=r-192; ip = w1; op = o1; K = 256;  N = 256;  kt = q & 7;  nt = q >> 3; }  // out 8x8
  else if (r < 512) { int q=r-256; ip = w2; op = o2; K = 256;  N = 1024; kt = q & 7;  nt = q >> 3; }  // ff1 8x32
  else              { int q=r-512; ip = w3; op = o3; K = 1024; N = 256;  kt = q & 31; nt = q >> 5; }  // ff2 32x8
  ip += (size_t)layer * K * N;
  op += (size_t)layer * N * K;
  int k0 = kt * 32, n0 = nt * 32;
  int tx = threadIdx.x, ty = threadIdx.y;   // (32,8)
#pragma unroll
  for (int rr = 0; rr < 4; ++rr) {
    int k = ty + rr * 8;
    tile[k][tx] = ip[(size_t)(k0 + k) * N + (n0 + tx)];
  }
  __syncthreads();
#pragma unroll
  for (int rr = 0; rr < 4; ++rr) {
    int n = ty + rr * 8;
    __hip_bfloat16 v = __float2bfloat16(tile[tx][n]);
    op[(size_t)(n0 + n) * K + (k0 + tx)] = *(u16*)&v;
  }
}

// ---------------- bf16 MFMA GEMM 64x128, BK=64, LDS-swizzled (qkv layer 0): A@W+b -> f16 ----------------
__global__ __launch_bounds__(256, 3) void gemm_qkv64(
    const u16* __restrict__ A, const u16* __restrict__ Bt,
    const float* __restrict__ bias, f16* __restrict__ outH,
    int M, int N, int K) {
  __shared__ u16 As[64 * 64];
  __shared__ u16 Bs[128 * 64];
  int tid = threadIdx.x;
  int wave = tid >> 6, lane = tid & 63;
  int wm = wave & 1, wn = wave >> 1;              // wave = 32 rows x 64 cols
  int m0 = blockIdx.y * 64, n0 = blockIdx.x * 128;
  int lr = lane & 15, lq = lane >> 4;
  int swz = (lr & 7) << 3;

  vf4 acc[2][4];
#pragma unroll
  for (int i = 0; i < 2; ++i)
#pragma unroll
    for (int j = 0; j < 4; ++j) { acc[i][j][0]=0.f; acc[i][j][1]=0.f; acc[i][j][2]=0.f; acc[i][j][3]=0.f; }

  int srow = tid >> 3;                  // 0..31
  int sc = (tid & 7) * 8;
  int cswz = (((tid & 7) ^ (srow & 7)) * 8);
  const u16* ag = A + (size_t)(m0 + srow) * K + cswz;
  const u16* bg = Bt + (size_t)(n0 + srow) * K + cswz;
  u16* al = As + srow * 64 + sc;
  u16* bl = Bs + srow * 64 + sc;
  const size_t rstride32 = (size_t)32 * K;

  for (int k0 = 0; k0 < K; k0 += 64) {
#pragma unroll
    for (int r = 0; r < 2; ++r)
      gload16(ag + k0 + r * rstride32, al + r * 32 * 64);
#pragma unroll
    for (int r = 0; r < 4; ++r)
      gload16(bg + k0 + r * rstride32, bl + r * 32 * 64);
    __syncthreads();
#pragma unroll
    for (int kk = 0; kk < 2; ++kk) {
      vs8 av[2], bv[4];
#pragma unroll
      for (int i = 0; i < 2; ++i)
        av[i] = *(const vs8*)&As[(wm * 32 + i * 16 + lr) * 64 + ((kk * 32 + lq * 8) ^ swz)];
#pragma unroll
      for (int j = 0; j < 4; ++j)
        bv[j] = *(const vs8*)&Bs[(wn * 64 + j * 16 + lr) * 64 + ((kk * 32 + lq * 8) ^ swz)];
#pragma unroll
      for (int i = 0; i < 2; ++i)
#pragma unroll
        for (int j = 0; j < 4; ++j)
          acc[i][j] = __builtin_amdgcn_mfma_f32_16x16x32_bf16(av[i], bv[j], acc[i][j], 0, 0, 0);
    }
    __syncthreads();
  }

#pragma unroll
  for (int i = 0; i < 2; ++i) {
    int row0 = m0 + wm * 32 + i * 16 + lq * 4;
#pragma unroll
    for (int j = 0; j < 4; ++j) {
      int col = n0 + wn * 64 + j * 16 + lr;
      float bb = bias[col];
#pragma unroll
      for (int r = 0; r < 4; ++r)
        outH[(size_t)(row0 + r) * N + col] = (f16)(acc[i][j][r] + bb);
    }
  }
}

// ---------------- fused GEMM1 (N=256) + bias + residual + LN -> bf16 (+f32) + optional GEMM2 ----------------
// GEMM1 = R16's gemm_ln (BK=64, simple barrier loop, LDS swizzled). When OfA != null the A-staging
// reads attn kv-split partials Of[0]+Of[1] scaled by 1/(l0+l1) (combine fused, math identical).
// R18 phase 2: LN output (= the 32 rows this block just produced) is bounced into swizzled
// As2[32][256]; then C2 = LNout @ Bt2 + bias2 over n-chunks of 256 (K=256 resident in As2).
// out2H!=null -> f16 plain (qkv for next layer); else out2B with relu (ff1 -> hB).
__global__ __launch_bounds__(512, 2) void gemm_ln2(
    const u16* __restrict__ A, const u16* __restrict__ Bt,
    const float* __restrict__ bias, const __hip_bfloat16* __restrict__ res,
    const float* __restrict__ gam, const float* __restrict__ bet,
    __hip_bfloat16* __restrict__ outB, float* __restrict__ outF, int K,
    const f16* __restrict__ OfA, const float* __restrict__ lf,
    const u16* __restrict__ Bt2, const float* __restrict__ bias2, int N2,
    __hip_bfloat16* __restrict__ out2B, f16* __restrict__ out2H) {
  __shared__ u16 As[32 * 64];
  __shared__ u16 Bs[256 * 64];
  __shared__ u16 As2[32 * 256];                   // phase-2 A (LN output), swizzled
  __shared__ u16 Bs2[256 * 64];                   // phase-2 B tile
  __shared__ float ps[4][32], ps2[4][32], mur[32], rsr[32];
  __shared__ float invs[8][32];                    // 1/(l0+l1) per (head, local row)
  int tid = threadIdx.x;
  int wave = tid >> 6, lane = tid & 63;
  int wm = wave & 1, wn = wave >> 1;              // wn 0..3
  int lr = lane & 15, lq = lane >> 4;
  int m0 = blockIdx.x * 32;
  int swz = (lr & 7) << 3;

  vf4 acc[4];
#pragma unroll
  for (int j = 0; j < 4; ++j) { acc[j][0]=0.f; acc[j][1]=0.f; acc[j][2]=0.f; acc[j][3]=0.f; }

  int sr = tid >> 3;                    // 0..63 (A-path uses 0..31 via tid<256 guard)
  int sc = (tid & 7) * 8;
  int cswz = (((tid & 7) ^ (sr & 7)) * 8);
  const u16* ag = A + (size_t)(m0 + sr) * K + cswz;
  const u16* bg = Bt + (size_t)sr * K + cswz;     // rows 0..63; +64/128/192 in loop
  u16* al = As + sr * 64 + sc;
  u16* bl = Bs + sr * 64 + sc;

  if (OfA) {
    if (tid < 256) {
      int h = tid >> 5, rl = tid & 31;
      int row = m0 + rl, bb_ = row >> 11, t = row & 2047;
      int g = bb_ * 8 + h;
      invs[h][rl] = 1.0f / (lf[g * 2048 + t] + lf[65536 + g * 2048 + t]);
    }
    __syncthreads();
  }

  for (int k0 = 0; k0 < K; k0 += 64) {
    if (tid < 256) {
      if (OfA) {
        // rows 0..31; logical k-col = k0 + cswz (pre-swizzled), dest linear
        size_t off = (size_t)(m0 + sr) * 256 + k0 + cswz;
        vh8 a0 = *(const vh8*)(OfA + off);
        vh8 a1 = *(const vh8*)(OfA + 2097152 + off);
        float inv = invs[(k0 + cswz) >> 5][sr];
        union { vs8 v; u16 u[8]; } pk;
#pragma unroll
        for (int j = 0; j < 8; ++j) {
          __hip_bfloat16 hb = __float2bfloat16(((float)a0[j] + (float)a1[j]) * inv);
          pk.u[j] = *(u16*)&hb;
        }
        *(vs8*)al = pk.v;
      } else {
        gload16(ag + k0, al);
      }
    }
#pragma unroll
    for (int r = 0; r < 4; ++r)
      gload16(bg + k0 + (size_t)(r * 64) * K, bl + r * 64 * 64);
    __syncthreads();
#pragma unroll
    for (int kk = 0; kk < 2; ++kk) {
      vs8 av, bv[4];
      av = *(const vs8*)&As[(wm * 16 + lr) * 64 + ((kk * 32 + lq * 8) ^ swz)];
#pragma unroll
      for (int j = 0; j < 4; ++j)
        bv[j] = *(const vs8*)&Bs[(wn * 64 + j * 16 + lr) * 64 + ((kk * 32 + lq * 8) ^ swz)];
#pragma unroll
      for (int j = 0; j < 4; ++j)
        acc[j] = __builtin_amdgcn_mfma_f32_16x16x32_bf16(av, bv[j], acc[j], 0, 0, 0);
    }
    __syncthreads();
  }

  float sum_[4], sq_[4];
#pragma unroll
  for (int r = 0; r < 4; ++r) { sum_[r] = 0.f; sq_[r] = 0.f; }
#pragma unroll
  for (int j = 0; j < 4; ++j) {
    int col = wn * 64 + j * 16 + lr;
    float bb = bias[col];
#pragma unroll
    for (int r = 0; r < 4; ++r) {
      int row = m0 + wm * 16 + lq * 4 + r;
      float v = acc[j][r] + bb + __bfloat162float(res[(size_t)row * 256 + col]);
      acc[j][r] = v;
      sum_[r] += v;
      sq_[r] += v * v;
    }
  }
#pragma unroll
  for (int r = 0; r < 4; ++r) {
#pragma unroll
    for (int m = 1; m <= 8; m <<= 1) {
      sum_[r] += __shfl_xor(sum_[r], m);
      sq_[r]  += __shfl_xor(sq_[r], m);
    }
  }
  if (lr == 0) {
#pragma unroll
    for (int r = 0; r < 4; ++r) {
      int rl = wm * 16 + lq * 4 + r;
      ps[wn][rl] = sum_[r];
      ps2[wn][rl] = sq_[r];
    }
  }
  __syncthreads();
  if (tid < 32) {
    float s = ps[0][tid] + ps[1][tid] + ps[2][tid] + ps[3][tid];
    float s2 = ps2[0][tid] + ps2[1][tid] + ps2[2][tid] + ps2[3][tid];
    float mu = s * (1.0f / 256.0f);
    float var = s2 * (1.0f / 256.0f) - mu * mu;
    mur[tid] = mu;
    rsr[tid] = rsqrtf(var + 1e-5f);
  }
  __syncthreads();
#pragma unroll
  for (int r = 0; r < 4; ++r) {
    int rl = wm * 16 + lq * 4 + r;
    float mu = mur[rl], rs = rsr[rl];
    int row = m0 + rl;
#pragma unroll
    for (int j = 0; j < 4; ++j) {
      int col = wn * 64 + j * 16 + lr;
      float o = (acc[j][r] - mu) * rs * gam[col] + bet[col];
      size_t idx = (size_t)row * 256 + col;
      __hip_bfloat16 ob = __float2bfloat16(o);
      outB[idx] = ob;
      if (outF) outF[idx] = o;
      if (N2) As2[rl * 256 + (col ^ ((rl & 7) << 3))] = *(u16*)&ob;   // bounce for phase 2
    }
  }

  // ---------------- phase 2: C2 = LNout @ Bt2 + bias2 (K=256 resident in As2) ----------------
  if (N2 > 0) {
    __syncthreads();                               // As2 complete
    int rowb = tid >> 3, cgb = tid & 7;            // Bs2 staging map
    int cswzb = ((cgb ^ (rowb & 7)) * 8);
    const u16* bg2 = Bt2 + (size_t)rowb * 256 + cswzb;
    u16* bl2 = Bs2 + rowb * 64 + cgb * 8;
    int nch = N2 >> 8;
    for (int nc = 0; nc < nch; ++nc) {
      vf4 a2[4];
#pragma unroll
      for (int j = 0; j < 4; ++j) { a2[j][0]=0.f; a2[j][1]=0.f; a2[j][2]=0.f; a2[j][3]=0.f; }
#pragma unroll
      for (int ks = 0; ks < 4; ++ks) {
#pragma unroll
        for (int i = 0; i < 4; ++i)
          gload16(bg2 + (size_t)(nc * 256 + i * 64) * 256 + ks * 64, bl2 + i * 64 * 64);
        __syncthreads();
#pragma unroll
        for (int kk = 0; kk < 2; ++kk) {
          vs8 av2 = *(const vs8*)&As2[(wm * 16 + lr) * 256 + ((ks * 64 + kk * 32 + lq * 8) ^ swz)];
          vs8 bv;
#pragma unroll
          for (int j = 0; j < 4; ++j) {
            bv = *(const vs8*)&Bs2[(wn * 64 + j * 16 + lr) * 64 + ((kk * 32 + lq * 8) ^ swz)];
            a2[j] = __builtin_amdgcn_mfma_f32_16x16x32_bf16(av2, bv, a2[j], 0, 0, 0);
          }
        }
        __syncthreads();
      }
#pragma unroll
      for (int j = 0; j < 4; ++j) {
        int col = nc * 256 + wn * 64 + j * 16 + lr;
        float bb2 = bias2[col];
#pragma unroll
        for (int r = 0; r < 4; ++r) {
          int row = m0 + wm * 16 + lq * 4 + r;
          float v = a2[j][r] + bb2;
          if (out2H) out2H[(size_t)row * N2 + col] = (f16)v;
          else       out2B[(size_t)row * N2 + col] = __float2bfloat16(fmaxf(v, 0.0f));
        }
      }
    }
  }
}

// ---------------- MFMA flash attention v7: kv-split 2, + setprio on MFMA cluster ----------------
// No running max is tracked (bounded logits -> raw exp2), so partials combine ADDITIVELY:
// O = O0+O1, l = l0+l1. Grid 512 -> 2 blocks/CU. Partials are normalized inside gemm_ln2 (LN1).
__global__ __launch_bounds__(512, 4) void attn_mfma(const f16* __restrict__ qkv,
                                                    f16* __restrict__ Of,
                                                    float* __restrict__ lf) {
  // per buf: K [128][40] u16 = 5120 | VT [32][132] f16 = 4224 -> 9344 u16; x2 bufs = 37376 B
  __shared__ __align__(16) u16 lds[2][9344];
  int tid = threadIdx.x;
  int wave = tid >> 6, lane = tid & 63;
  int lr = lane & 15, quad = lane >> 4;

  int id = blockIdx.x;
  int xcd = id & 7, slot = id >> 3;                // slot 0..63
  int grp = xcd * 4 + (slot & 3);                  // 32 (b,h) groups
  int qt = (slot >> 2) & 7;                        // 8 q-tiles of 256 rows
  int split = slot >> 5;                           // kv half: 0 or 1
  int b = grp >> 3, h = grp & 7;
  int q0 = qt * 256;
  int kv0 = split << 10;                           // 0 or 1024
  int rowbase = b * 2048;
  const f16* base_bh = qkv + (size_t)rowbase * 768 + h * 96;

  vh8 qf[2];
#pragma unroll
  for (int nt = 0; nt < 2; ++nt) {
    int qr = q0 + wave * 32 + nt * 16 + lr;
    vh8 t = *(const vh8*)(base_bh + (size_t)qr * 768 + quad * 8);
#pragma unroll
    for (int j = 0; j < 8; ++j) t[j] = t[j] * (f16)0.25508682f;
    qf[nt] = t;
  }

  vf4 O[2][2], lO[2];
#pragma unroll
  for (int a = 0; a < 2; ++a) {
    lO[a][0]=0.f; lO[a][1]=0.f; lO[a][2]=0.f; lO[a][3]=0.f;
#pragma unroll
    for (int d = 0; d < 2; ++d) { O[a][d][0]=0.f; O[a][d][1]=0.f; O[a][d][2]=0.f; O[a][d][3]=0.f; }
  }

  // staging maps: all 512 threads stage K (1 vh8) and V (2 vh4 -> 4 vh2) per chunk
  int srK = tid >> 2;                  // 0..127
  int scK = (tid & 3) * 8;
  const f16* kg = base_bh + (size_t)(kv0 + srK) * 768 + 32 + scK;
  int kvp = tid >> 3;                  // 0..63 -> rows 2kvp, 2kvp+1
  int d4 = (tid & 7) * 4;
  const f16* vg = base_bh + (size_t)(kv0 + kvp * 2) * 768 + 64 + d4;

  const vf4 z4 = {0.f, 0.f, 0.f, 0.f};
  const vh4 onesh = {(f16)1.0f, (f16)1.0f, (f16)1.0f, (f16)1.0f};
  const size_t cstep = (size_t)128 * 768;

  // stage chunk 0 into buf 0
  {
    vh8 k0 = *(const vh8*)kg;
    *(vh8*)&lds[0][srK * 40 + scK] = k0;
    vh4 a = *(const vh4*)vg;
    vh4 bb = *(const vh4*)(vg + 768);
    f16* vt0 = (f16*)&lds[0][5120];
#pragma unroll
    for (int i = 0; i < 4; ++i) {
      vh2 pr; pr[0] = a[i]; pr[1] = bb[i];
      *(vh2*)(vt0 + (d4 + i) * 132 + kvp * 2) = pr;
    }
  }
  __syncthreads();

  for (int c = 0; c < 8; ++c) {        // 8 chunks of 128 kv rows (this split's half)
    int cur = c & 1;
    const f16* Ks = (const f16*)&lds[cur][0];
    const f16* VT = (const f16*)&lds[cur][5120];

    vh8 kn; vh4 va, vb;
    if (c < 7) {                       // prefetch next chunk (hidden under 8-t16 compute)
      kn = *(const vh8*)(kg + (size_t)(c + 1) * cstep);
      const f16* vp = vg + (size_t)(c + 1) * cstep;
      va = *(const vh4*)vp;
      vb = *(const vh4*)(vp + 768);
    }

    __builtin_amdgcn_s_setprio(1);     // T5: favor this wave while in the MFMA/exp cluster
#pragma unroll
    for (int t16 = 0; t16 < 8; ++t16) {
      vh8 ak = *(const vh8*)&Ks[(t16 * 16 + lr) * 40 + quad * 8];
      vf4 s0 = __builtin_amdgcn_mfma_f32_16x16x32_f16(ak, qf[0], z4, 0, 0, 0);
      vf4 s1 = __builtin_amdgcn_mfma_f32_16x16x32_f16(ak, qf[1], z4, 0, 0, 0);
      vh4 p0, p1;
      ((hw2*)&p0)[0] = __builtin_amdgcn_cvt_pkrtz(fexp2(s0[0]), fexp2(s0[1]));
      ((hw2*)&p0)[1] = __builtin_amdgcn_cvt_pkrtz(fexp2(s0[2]), fexp2(s0[3]));
      ((hw2*)&p1)[0] = __builtin_amdgcn_cvt_pkrtz(fexp2(s1[0]), fexp2(s1[1]));
      ((hw2*)&p1)[1] = __builtin_amdgcn_cvt_pkrtz(fexp2(s1[2]), fexp2(s1[3]));
      vh4 vf0 = *(const vh4*)&VT[(0 * 16 + lr) * 132 + t16 * 16 + quad * 4];
      vh4 vf1 = *(const vh4*)&VT[(1 * 16 + lr) * 132 + t16 * 16 + quad * 4];
      O[0][0] = __builtin_amdgcn_mfma_f32_16x16x16f16(p0, vf0, O[0][0], 0, 0, 0);
      O[0][1] = __builtin_amdgcn_mfma_f32_16x16x16f16(p0, vf1, O[0][1], 0, 0, 0);
      O[1][0] = __builtin_amdgcn_mfma_f32_16x16x16f16(p1, vf0, O[1][0], 0, 0, 0);
      O[1][1] = __builtin_amdgcn_mfma_f32_16x16x16f16(p1, vf1, O[1][1], 0, 0, 0);
      lO[0] = __builtin_amdgcn_mfma_f32_16x16x16f16(p0, onesh, lO[0], 0, 0, 0);
      lO[1] = __builtin_amdgcn_mfma_f32_16x16x16f16(p1, onesh, lO[1], 0, 0, 0);
    }
    __builtin_amdgcn_s_setprio(0);

    if (c < 7) {                       // write prefetched chunk into the other buffer
      *(vh8*)&lds[cur ^ 1][srK * 40 + scK] = kn;
      f16* vt1 = (f16*)&lds[cur ^ 1][5120];
#pragma unroll
      for (int i = 0; i < 4; ++i) {
        vh2 pr; pr[0] = va[i]; pr[1] = vb[i];
        *(vh2*)(vt1 + (d4 + i) * 132 + kvp * 2) = pr;
      }
    }
    __syncthreads();
  }

  // epilogue: write UNNORMALIZED partial O (f16) + row-sum l (f32); LN1 normalizes
#pragma unroll
  for (int nt = 0; nt < 2; ++nt) {
#pragma unroll
    for (int r = 0; r < 4; ++r) {
      int tq = q0 + wave * 32 + nt * 16 + quad * 4 + r;    // t index 0..2047
      if (lr == 0) lf[split * 65536 + grp * 2048 + tq] = lO[nt][r];
      int row = rowbase + tq;
#pragma unroll
      for (int dt = 0; dt < 2; ++dt) {
        int col = h * 32 + dt * 16 + lr;
        Of[(size_t)split * 2097152 + (size_t)row * 256 + col] = (f16)O[nt][dt][r];
      }
    }
  }
}

// ---------------- driver ----------------
extern "C" void kernel_launch(void* const* d_in, const int* in_sizes, int n_in,
                              void* d_out, int out_size, void* d_ws, size_t ws_size,
                              hipStream_t stream) {
  (void)in_sizes; (void)n_in; (void)out_size; (void)ws_size;
  const float* x     = (const float*)d_in[0];
  const float* qkv_b = (const float*)d_in[2];
  const float* out_b = (const float*)d_in[4];
  const float* ff1_b = (const float*)d_in[6];
  const float* ff2_b = (const float*)d_in[8];
  const float* ln1_g = (const float*)d_in[9];
  const float* ln1_b = (const float*)d_in[10];
  const float* ln2_g = (const float*)d_in[11];
  const float* ln2_b = (const float*)d_in[12];

  // ws layout (bytes); total = 52,428,800 (ws is 268 MB)
  //   [0, 8388608)           Of: attn partial O f16 [2][8192][256]
  //   [8388608, 12582912)    Xb: bf16 carried state (4 MB)
  //   [12582912, 13107200)   lf: attn partial l f32 [2][32][2048] (512 KB)
  //   [16777216, 29360128)   qkvH f16 8192x768 (12.6 MB)  -- DISJOINT from hB now (ln2qkv
  //   [29360128, 46137344)   hB bf16 8192x1024 (16.8 MB)      reads hB while writing qkvH)
  //   [46137344, 52428800)   transposed bf16 weights
  char* ws = (char*)d_ws;
  f16*            Of    = (f16*)(ws + 0);
  __hip_bfloat16* Xb    = (__hip_bfloat16*)(ws + 8388608);
  float*          lf    = (float*)(ws + 12582912);
  f16*            qkvH  = (f16*)(ws + 16777216);
  __hip_bfloat16* hB    = (__hip_bfloat16*)(ws + 29360128);
  u16* qkvwT = (u16*)(ws + 46137344);  // [L][768][256]  (1,572,864 B)
  u16* outwT = (u16*)(ws + 47710208);  // [L][256][256]  (524,288 B)
  u16* ff1wT = (u16*)(ws + 48234496);  // [L][1024][256] (2,097,152 B)
  u16* ff2wT = (u16*)(ws + 50331648);  // [L][256][1024] (2,097,152 B) ends 52,428,800

  pe_kernel<<<2048, 256, 0, stream>>>(x, Xb);
  transpose_cast_all<<<3072, dim3(32, 8), 0, stream>>>(
      (const float*)d_in[1], (const float*)d_in[3], (const float*)d_in[5], (const float*)d_in[7],
      qkvwT, outwT, ff1wT, ff2wT);

  // layer-0 qkv (standalone); subsequent qkv fused into the previous layer's LN2 kernel
  gemm_qkv64<<<dim3(6, 128), 256, 0, stream>>>((const u16*)Xb, qkvwT,
      qkv_b, qkvH, 8192, 768, 256);

  for (int l = 0; l < 4; ++l) {
    // attn partials (kv-split 2, 2 blocks/CU, XCD-pinned)
    attn_mfma<<<512, 512, 0, stream>>>(qkvH, Of, lf);
    // Xb = LN1((O0+O1)/l @ out_w + b + Xb); then hB = relu(Xb @ W1 + b1)   [fused]
    gemm_ln2<<<256, 512, 0, stream>>>(nullptr, outwT + (size_t)l * 256 * 256,
        out_b + l * 256, Xb, ln1_g + l * 256, ln1_b + l * 256, Xb, nullptr, 256, Of, lf,
        ff1wT + (size_t)l * 1024 * 256, ff1_b + l * 1024, 1024, hB, nullptr);
    // Xb = LN2(h @ W2 + b2 + Xb) (+d_out f32 on last); then qkvH = Xb @ Wqkv[l+1] + b  [fused]
    float* lnout = (l == 3) ? (float*)d_out : nullptr;
    const u16* nqw = (l < 3) ? (qkvwT + (size_t)(l + 1) * 768 * 256) : nullptr;
    const float* nqb = (l < 3) ? (qkv_b + (l + 1) * 768) : qkv_b;
    int n2 = (l < 3) ? 768 : 0;
    gemm_ln2<<<256, 512, 0, stream>>>((const u16*)hB, ff2wT + (size_t)l * 256 * 1024,
        ff2_b + l * 256, Xb, ln2_g + l * 256, ln2_b + l * 256, Xb, lnout, 1024, nullptr, nullptr,
        nqw, nqb, n2, nullptr, qkvH);
  }
}

// Round 7
// 401.436 us; speedup vs baseline: 1.0912x; 1.0912x over previous
//
#include <hip/hip_runtime.h>
#include <hip/hip_bf16.h>
#include <stdint.h>

typedef unsigned short u16;
typedef _Float16 f16;
typedef short vs8 __attribute__((ext_vector_type(8)));   // 8 x bf16 bits (MFMA A/B frag)
typedef float vf4 __attribute__((ext_vector_type(4)));   // MFMA C/D frag
typedef _Float16 vh2 __attribute__((ext_vector_type(2)));
typedef _Float16 vh4 __attribute__((ext_vector_type(4)));
typedef _Float16 vh8 __attribute__((ext_vector_type(8)));
typedef __fp16 hw2 __attribute__((ext_vector_type(2)));  // cvt_pkrtz return type

// Problem constants: B=4 T=2048 E=256 H=8 HD=32 FE=4 L=4
//
// R16: XOR-swizzled GEMM LDS tiles (bank-conflict fix): -39 us, confirmed. BEST = 401.9.
// R17: counted-vmcnt 2-phase graft on gemm_ln: +33 REGRESSION (wrong regime). Reverted.
// R18: LN+next-GEMM fusion: +36 REGRESSION (moved GEMMs into 1-block/CU serial phase-2,
//      destroying the multi-block overlap that makes the standalone kernels fast). Reverted.
// R19: gemm_ln was the only 1-block/CU kernel (grid 256) -> no co-resident block to hide
//      its per-k-step stage/drain. Split M 32->16 rows/block: grid 512 = 2 blocks/CU,
//      256 threads (4 waves x 16 rows x 64 cols). Same per-wave MFMA & aggregate staging;
//      partner block hides the drain (same mechanism as gemm_relu/qkv/attn).

__device__ __forceinline__ void gload16(const u16* g, u16* l) {
  __builtin_amdgcn_global_load_lds((const __attribute__((address_space(1))) void*)g,
                                   (__attribute__((address_space(3))) void*)l,
                                   16, 0, 0);
}

__device__ __forceinline__ float fexp2(float x) {
#if __has_builtin(__builtin_amdgcn_exp2f)
  return __builtin_amdgcn_exp2f(x);
#else
  return __expf(x * 0.69314718056f);
#endif
}

// ---------------- Fourier PE -> bf16 (fast trig: exp2 + hw sin/cos in revolutions) ----------------
__global__ void pe_kernel(const float* __restrict__ x, __hip_bfloat16* __restrict__ Xb) {
  int gid = blockIdx.x * 256 + threadIdx.x;   // 0..524287
  int row = gid >> 6;                          // 0..8191 (64 thr/row, 4 elems each)
  int e0 = (gid & 63) * 4;                     // 0..252, 4-aligned; same side of 128
  int t = row & 2047;
  int f0 = (e0 < 128) ? e0 : (e0 - 128);
  const float c = -13.287712379549449f / 128.0f;   // -log2(10000)/128
  const float inv2pi = 0.15915494309189535f;
  float4 xv = *(const float4*)(x + (size_t)row * 256 + e0);
  u16 o[4];
#pragma unroll
  for (int j = 0; j < 4; ++j) {
    float freq = fexp2(c * (float)(f0 + j));
    float rev = (float)t * freq * inv2pi;
    rev = rev - floorf(rev);
    float pe = (e0 < 128) ? __builtin_amdgcn_sinf(rev) : __builtin_amdgcn_cosf(rev);
    float xin = (j == 0) ? xv.x : (j == 1) ? xv.y : (j == 2) ? xv.z : xv.w;
    __hip_bfloat16 hb = __float2bfloat16(xin + pe);
    o[j] = *(u16*)&hb;
  }
  *(uint2*)((u16*)Xb + (size_t)row * 256 + e0) = *(uint2*)o;
}

// ---------------- merged weight transpose + cast: f32 [L][K][N] -> bf16 [L][N][K] ----------------
__global__ void transpose_cast_all(
    const float* __restrict__ w0, const float* __restrict__ w1,
    const float* __restrict__ w2, const float* __restrict__ w3,
    u16* __restrict__ o0, u16* __restrict__ o1,
    u16* __restrict__ o2, u16* __restrict__ o3) {
  __shared__ float tile[32][33];
  int flat = blockIdx.x;                 // 0..3071
  int layer = flat / 768;
  int r = flat - layer * 768;
  const float* ip; u16* op; int K, N, kt, nt;
  if (r < 192)      {              ip = w0; op = o0; K = 256;  N = 768;  kt = r & 7;  nt = r >> 3; }  // qkv 8x24
  else if (r < 256) { int q=r-192; ip = w1; op = o1; K = 256;  N = 256;  kt = q & 7;  nt = q >> 3; }  // out 8x8
  else if (r < 512) { int q=r-256; ip = w2; op = o2; K = 256;  N = 1024; kt = q & 7;  nt = q >> 3; }  // ff1 8x32
  else              { int q=r-512; ip = w3; op = o3; K = 1024; N = 256;  kt = q & 31; nt = q >> 5; }  // ff2 32x8
  ip += (size_t)layer * K * N;
  op += (size_t)layer * N * K;
  int k0 = kt * 32, n0 = nt * 32;
  int tx = threadIdx.x, ty = threadIdx.y;   // (32,8)
#pragma unroll
  for (int rr = 0; rr < 4; ++rr) {
    int k = ty + rr * 8;
    tile[k][tx] = ip[(size_t)(k0 + k) * N + (n0 + tx)];
  }
  __syncthreads();
#pragma unroll
  for (int rr = 0; rr < 4; ++rr) {
    int n = ty + rr * 8;
    __hip_bfloat16 v = __float2bfloat16(tile[tx][n]);
    op[(size_t)(n0 + n) * K + (k0 + tx)] = *(u16*)&v;
  }
}

// ---------------- bf16 MFMA GEMM 128x128, BK=64, LDS-swizzled (ff1): relu(A@W+b) -> bf16 ----------------
__global__ __launch_bounds__(256, 2) void gemm_relu(
    const u16* __restrict__ A, const u16* __restrict__ Bt,
    const float* __restrict__ bias, __hip_bfloat16* __restrict__ outB,
    int M, int N, int K) {
  __shared__ u16 As[128 * 64];
  __shared__ u16 Bs[128 * 64];
  int tid = threadIdx.x;
  int wave = tid >> 6, lane = tid & 63;
  int wm = wave & 1, wn = wave >> 1;              // 2x2 waves of 64x64
  int m0 = blockIdx.y * 128, n0 = blockIdx.x * 128;
  int lr = lane & 15, lq = lane >> 4;
  int swz = (lr & 7) << 3;                        // read-side XOR (elems)

  vf4 acc[4][4];
#pragma unroll
  for (int i = 0; i < 4; ++i)
#pragma unroll
    for (int j = 0; j < 4; ++j) {
      acc[i][j][0] = 0.f; acc[i][j][1] = 0.f; acc[i][j][2] = 0.f; acc[i][j][3] = 0.f;
    }

  int srow = tid >> 3;                  // 0..31 (+32*r rounds; &7 invariant)
  int sc = (tid & 7) * 8;               // linear LDS dest col (elems)
  int cswz = (((tid & 7) ^ (srow & 7)) * 8);   // pre-swizzled GLOBAL source col
  const u16* ag = A + (size_t)(m0 + srow) * K + cswz;
  const u16* bg = Bt + (size_t)(n0 + srow) * K + cswz;
  u16* al = As + srow * 64 + sc;
  u16* bl = Bs + srow * 64 + sc;
  const size_t rstride32 = (size_t)32 * K;

  for (int k0 = 0; k0 < K; k0 += 64) {
#pragma unroll
    for (int r = 0; r < 4; ++r) {
      gload16(ag + k0 + r * rstride32, al + r * 32 * 64);
      gload16(bg + k0 + r * rstride32, bl + r * 32 * 64);
    }
    __syncthreads();
#pragma unroll
    for (int kk = 0; kk < 2; ++kk) {
      vs8 av[4], bv[4];
#pragma unroll
      for (int i = 0; i < 4; ++i)
        av[i] = *(const vs8*)&As[(wm * 64 + i * 16 + lr) * 64 + ((kk * 32 + lq * 8) ^ swz)];
#pragma unroll
      for (int j = 0; j < 4; ++j)
        bv[j] = *(const vs8*)&Bs[(wn * 64 + j * 16 + lr) * 64 + ((kk * 32 + lq * 8) ^ swz)];
#pragma unroll
      for (int i = 0; i < 4; ++i)
#pragma unroll
        for (int j = 0; j < 4; ++j)
          acc[i][j] = __builtin_amdgcn_mfma_f32_16x16x32_bf16(av[i], bv[j], acc[i][j], 0, 0, 0);
    }
    __syncthreads();
  }

#pragma unroll
  for (int i = 0; i < 4; ++i) {
    int row0 = m0 + wm * 64 + i * 16 + lq * 4;
#pragma unroll
    for (int j = 0; j < 4; ++j) {
      int col = n0 + wn * 64 + j * 16 + lr;
      float bb = bias[col];
#pragma unroll
      for (int r = 0; r < 4; ++r) {
        size_t idx = (size_t)(row0 + r) * N + col;
        outB[idx] = __float2bfloat16(fmaxf(acc[i][j][r] + bb, 0.0f));
      }
    }
  }
}

// ---------------- bf16 MFMA GEMM 64x128, BK=64, LDS-swizzled (qkv): A@W+b -> f16 ----------------
__global__ __launch_bounds__(256, 3) void gemm_qkv64(
    const u16* __restrict__ A, const u16* __restrict__ Bt,
    const float* __restrict__ bias, f16* __restrict__ outH,
    int M, int N, int K) {
  __shared__ u16 As[64 * 64];
  __shared__ u16 Bs[128 * 64];
  int tid = threadIdx.x;
  int wave = tid >> 6, lane = tid & 63;
  int wm = wave & 1, wn = wave >> 1;              // wave = 32 rows x 64 cols
  int m0 = blockIdx.y * 64, n0 = blockIdx.x * 128;
  int lr = lane & 15, lq = lane >> 4;
  int swz = (lr & 7) << 3;

  vf4 acc[2][4];
#pragma unroll
  for (int i = 0; i < 2; ++i)
#pragma unroll
    for (int j = 0; j < 4; ++j) { acc[i][j][0]=0.f; acc[i][j][1]=0.f; acc[i][j][2]=0.f; acc[i][j][3]=0.f; }

  int srow = tid >> 3;                  // 0..31
  int sc = (tid & 7) * 8;
  int cswz = (((tid & 7) ^ (srow & 7)) * 8);
  const u16* ag = A + (size_t)(m0 + srow) * K + cswz;
  const u16* bg = Bt + (size_t)(n0 + srow) * K + cswz;
  u16* al = As + srow * 64 + sc;
  u16* bl = Bs + srow * 64 + sc;
  const size_t rstride32 = (size_t)32 * K;

  for (int k0 = 0; k0 < K; k0 += 64) {
#pragma unroll
    for (int r = 0; r < 2; ++r)
      gload16(ag + k0 + r * rstride32, al + r * 32 * 64);
#pragma unroll
    for (int r = 0; r < 4; ++r)
      gload16(bg + k0 + r * rstride32, bl + r * 32 * 64);
    __syncthreads();
#pragma unroll
    for (int kk = 0; kk < 2; ++kk) {
      vs8 av[2], bv[4];
#pragma unroll
      for (int i = 0; i < 2; ++i)
        av[i] = *(const vs8*)&As[(wm * 32 + i * 16 + lr) * 64 + ((kk * 32 + lq * 8) ^ swz)];
#pragma unroll
      for (int j = 0; j < 4; ++j)
        bv[j] = *(const vs8*)&Bs[(wn * 64 + j * 16 + lr) * 64 + ((kk * 32 + lq * 8) ^ swz)];
#pragma unroll
      for (int i = 0; i < 2; ++i)
#pragma unroll
        for (int j = 0; j < 4; ++j)
          acc[i][j] = __builtin_amdgcn_mfma_f32_16x16x32_bf16(av[i], bv[j], acc[i][j], 0, 0, 0);
    }
    __syncthreads();
  }

#pragma unroll
  for (int i = 0; i < 2; ++i) {
    int row0 = m0 + wm * 32 + i * 16 + lq * 4;
#pragma unroll
    for (int j = 0; j < 4; ++j) {
      int col = n0 + wn * 64 + j * 16 + lr;
      float bb = bias[col];
#pragma unroll
      for (int r = 0; r < 4; ++r)
        outH[(size_t)(row0 + r) * N + col] = (f16)(acc[i][j][r] + bb);
    }
  }
}

// ---------------- fused GEMM (N=256) + bias + bf16 residual + LN -> bf16 (+f32 opt) ----------------
// R19: 16 rows/block, 256 threads (4 waves, wn 0..3; wave = 16 rows x 64 cols), grid 512 =
// 2 blocks/CU. Body identical to R16's (BK=64 simple barrier loop, XOR-swizzled tiles).
// When OfA != null (LN1): A-staging reads kv-split partials Of[0]+Of[1], scales by precomputed
// 1/(l0+l1), converts to bf16, ds_writes (combine fused; math identical).
__global__ __launch_bounds__(256, 2) void gemm_ln(
    const u16* __restrict__ A, const u16* __restrict__ Bt,
    const float* __restrict__ bias, const __hip_bfloat16* __restrict__ res,
    const float* __restrict__ gam, const float* __restrict__ bet,
    __hip_bfloat16* __restrict__ outB, float* __restrict__ outF, int K,
    const f16* __restrict__ OfA, const float* __restrict__ lf) {
  __shared__ u16 As[16 * 64];
  __shared__ u16 Bs[256 * 64];
  __shared__ float ps[4][16], ps2[4][16], mur[16], rsr[16];
  __shared__ float invs[8][16];                    // 1/(l0+l1) per (head, local row)
  int tid = threadIdx.x;
  int wave = tid >> 6, lane = tid & 63;
  int wn = wave;                                   // 0..3 (single row-group)
  int lr = lane & 15, lq = lane >> 4;
  int m0 = blockIdx.x * 16;
  int swz = (lr & 7) << 3;

  vf4 acc[4];
#pragma unroll
  for (int j = 0; j < 4; ++j) { acc[j][0]=0.f; acc[j][1]=0.f; acc[j][2]=0.f; acc[j][3]=0.f; }

  // A-staging: 16 rows x 64 cols/step = 128 vh8 -> tid<128
  int srA = tid >> 3;                   // 0..31 (A uses 0..15 via tid<128)
  int scA = (tid & 7) * 8;
  int cswzA = (((tid & 7) ^ (srA & 7)) * 8);
  const u16* ag = A + (size_t)(m0 + srA) * K + cswzA;
  u16* al = As + srA * 64 + scA;
  // B-staging: 256 rows x 64 cols/step = 2048 vh8 -> 8 rounds of 32 rows
  const u16* bg = Bt + (size_t)srA * K + cswzA;   // rows srA + 32*r; (srA+32r)&7 == srA&7
  u16* bl = Bs + srA * 64 + scA;

  if (OfA) {
    if (tid < 128) {
      int h = tid >> 4, rl = tid & 15;
      int row = m0 + rl, bb_ = row >> 11, t = row & 2047;
      int g = bb_ * 8 + h;
      invs[h][rl] = 1.0f / (lf[g * 2048 + t] + lf[65536 + g * 2048 + t]);
    }
    __syncthreads();
  }

  for (int k0 = 0; k0 < K; k0 += 64) {
    if (tid < 128) {
      if (OfA) {
        // rows 0..15; logical k-col = k0 + cswzA (pre-swizzled), dest linear
        size_t off = (size_t)(m0 + srA) * 256 + k0 + cswzA;
        vh8 a0 = *(const vh8*)(OfA + off);
        vh8 a1 = *(const vh8*)(OfA + 2097152 + off);
        float inv = invs[(k0 + cswzA) >> 5][srA];
        union { vs8 v; u16 u[8]; } pk;
#pragma unroll
        for (int j = 0; j < 8; ++j) {
          __hip_bfloat16 hb = __float2bfloat16(((float)a0[j] + (float)a1[j]) * inv);
          pk.u[j] = *(u16*)&hb;
        }
        *(vs8*)al = pk.v;
      } else {
        gload16(ag + k0, al);
      }
    }
#pragma unroll
    for (int r = 0; r < 8; ++r)
      gload16(bg + k0 + (size_t)(r * 32) * K, bl + r * 32 * 64);
    __syncthreads();
#pragma unroll
    for (int kk = 0; kk < 2; ++kk) {
      vs8 av, bv[4];
      av = *(const vs8*)&As[lr * 64 + ((kk * 32 + lq * 8) ^ swz)];
#pragma unroll
      for (int j = 0; j < 4; ++j)
        bv[j] = *(const vs8*)&Bs[(wn * 64 + j * 16 + lr) * 64 + ((kk * 32 + lq * 8) ^ swz)];
#pragma unroll
      for (int j = 0; j < 4; ++j)
        acc[j] = __builtin_amdgcn_mfma_f32_16x16x32_bf16(av, bv[j], acc[j], 0, 0, 0);
    }
    __syncthreads();
  }

  float sum_[4], sq_[4];
#pragma unroll
  for (int r = 0; r < 4; ++r) { sum_[r] = 0.f; sq_[r] = 0.f; }
#pragma unroll
  for (int j = 0; j < 4; ++j) {
    int col = wn * 64 + j * 16 + lr;
    float bb = bias[col];
#pragma unroll
    for (int r = 0; r < 4; ++r) {
      int row = m0 + lq * 4 + r;
      float v = acc[j][r] + bb + __bfloat162float(res[(size_t)row * 256 + col]);
      acc[j][r] = v;
      sum_[r] += v;
      sq_[r] += v * v;
    }
  }
#pragma unroll
  for (int r = 0; r < 4; ++r) {
#pragma unroll
    for (int m = 1; m <= 8; m <<= 1) {
      sum_[r] += __shfl_xor(sum_[r], m);
      sq_[r]  += __shfl_xor(sq_[r], m);
    }
  }
  if (lr == 0) {
#pragma unroll
    for (int r = 0; r < 4; ++r) {
      int rl = lq * 4 + r;
      ps[wn][rl] = sum_[r];
      ps2[wn][rl] = sq_[r];
    }
  }
  __syncthreads();
  if (tid < 16) {
    float s = ps[0][tid] + ps[1][tid] + ps[2][tid] + ps[3][tid];
    float s2 = ps2[0][tid] + ps2[1][tid] + ps2[2][tid] + ps2[3][tid];
    float mu = s * (1.0f / 256.0f);
    float var = s2 * (1.0f / 256.0f) - mu * mu;
    mur[tid] = mu;
    rsr[tid] = rsqrtf(var + 1e-5f);
  }
  __syncthreads();
#pragma unroll
  for (int r = 0; r < 4; ++r) {
    int rl = lq * 4 + r;
    float mu = mur[rl], rs = rsr[rl];
    int row = m0 + rl;
#pragma unroll
    for (int j = 0; j < 4; ++j) {
      int col = wn * 64 + j * 16 + lr;
      float o = (acc[j][r] - mu) * rs * gam[col] + bet[col];
      size_t idx = (size_t)row * 256 + col;
      outB[idx] = __float2bfloat16(o);
      if (outF) outF[idx] = o;
    }
  }
}

// ---------------- MFMA flash attention v7: kv-split 2, + setprio on MFMA cluster ----------------
// No running max is tracked (bounded logits -> raw exp2), so partials combine ADDITIVELY:
// O = O0+O1, l = l0+l1. Grid 512 -> 2 blocks/CU. Partials are normalized inside gemm_ln (LN1).
__global__ __launch_bounds__(512, 4) void attn_mfma(const f16* __restrict__ qkv,
                                                    f16* __restrict__ Of,
                                                    float* __restrict__ lf) {
  // per buf: K [128][40] u16 = 5120 | VT [32][132] f16 = 4224 -> 9344 u16; x2 bufs = 37376 B
  __shared__ __align__(16) u16 lds[2][9344];
  int tid = threadIdx.x;
  int wave = tid >> 6, lane = tid & 63;
  int lr = lane & 15, quad = lane >> 4;

  int id = blockIdx.x;
  int xcd = id & 7, slot = id >> 3;                // slot 0..63
  int grp = xcd * 4 + (slot & 3);                  // 32 (b,h) groups
  int qt = (slot >> 2) & 7;                        // 8 q-tiles of 256 rows
  int split = slot >> 5;                           // kv half: 0 or 1
  int b = grp >> 3, h = grp & 7;
  int q0 = qt * 256;
  int kv0 = split << 10;                           // 0 or 1024
  int rowbase = b * 2048;
  const f16* base_bh = qkv + (size_t)rowbase * 768 + h * 96;

  vh8 qf[2];
#pragma unroll
  for (int nt = 0; nt < 2; ++nt) {
    int qr = q0 + wave * 32 + nt * 16 + lr;
    vh8 t = *(const vh8*)(base_bh + (size_t)qr * 768 + quad * 8);
#pragma unroll
    for (int j = 0; j < 8; ++j) t[j] = t[j] * (f16)0.25508682f;
    qf[nt] = t;
  }

  vf4 O[2][2], lO[2];
#pragma unroll
  for (int a = 0; a < 2; ++a) {
    lO[a][0]=0.f; lO[a][1]=0.f; lO[a][2]=0.f; lO[a][3]=0.f;
#pragma unroll
    for (int d = 0; d < 2; ++d) { O[a][d][0]=0.f; O[a][d][1]=0.f; O[a][d][2]=0.f; O[a][d][3]=0.f; }
  }

  // staging maps: all 512 threads stage K (1 vh8) and V (2 vh4 -> 4 vh2) per chunk
  int srK = tid >> 2;                  // 0..127
  int scK = (tid & 3) * 8;
  const f16* kg = base_bh + (size_t)(kv0 + srK) * 768 + 32 + scK;
  int kvp = tid >> 3;                  // 0..63 -> rows 2kvp, 2kvp+1
  int d4 = (tid & 7) * 4;
  const f16* vg = base_bh + (size_t)(kv0 + kvp * 2) * 768 + 64 + d4;

  const vf4 z4 = {0.f, 0.f, 0.f, 0.f};
  const vh4 onesh = {(f16)1.0f, (f16)1.0f, (f16)1.0f, (f16)1.0f};
  const size_t cstep = (size_t)128 * 768;

  // stage chunk 0 into buf 0
  {
    vh8 k0 = *(const vh8*)kg;
    *(vh8*)&lds[0][srK * 40 + scK] = k0;
    vh4 a = *(const vh4*)vg;
    vh4 bb = *(const vh4*)(vg + 768);
    f16* vt0 = (f16*)&lds[0][5120];
#pragma unroll
    for (int i = 0; i < 4; ++i) {
      vh2 pr; pr[0] = a[i]; pr[1] = bb[i];
      *(vh2*)(vt0 + (d4 + i) * 132 + kvp * 2) = pr;
    }
  }
  __syncthreads();

  for (int c = 0; c < 8; ++c) {        // 8 chunks of 128 kv rows (this split's half)
    int cur = c & 1;
    const f16* Ks = (const f16*)&lds[cur][0];
    const f16* VT = (const f16*)&lds[cur][5120];

    vh8 kn; vh4 va, vb;
    if (c < 7) {                       // prefetch next chunk (hidden under 8-t16 compute)
      kn = *(const vh8*)(kg + (size_t)(c + 1) * cstep);
      const f16* vp = vg + (size_t)(c + 1) * cstep;
      va = *(const vh4*)vp;
      vb = *(const vh4*)(vp + 768);
    }

    __builtin_amdgcn_s_setprio(1);     // T5: favor this wave while in the MFMA/exp cluster
#pragma unroll
    for (int t16 = 0; t16 < 8; ++t16) {
      vh8 ak = *(const vh8*)&Ks[(t16 * 16 + lr) * 40 + quad * 8];
      vf4 s0 = __builtin_amdgcn_mfma_f32_16x16x32_f16(ak, qf[0], z4, 0, 0, 0);
      vf4 s1 = __builtin_amdgcn_mfma_f32_16x16x32_f16(ak, qf[1], z4, 0, 0, 0);
      vh4 p0, p1;
      ((hw2*)&p0)[0] = __builtin_amdgcn_cvt_pkrtz(fexp2(s0[0]), fexp2(s0[1]));
      ((hw2*)&p0)[1] = __builtin_amdgcn_cvt_pkrtz(fexp2(s0[2]), fexp2(s0[3]));
      ((hw2*)&p1)[0] = __builtin_amdgcn_cvt_pkrtz(fexp2(s1[0]), fexp2(s1[1]));
      ((hw2*)&p1)[1] = __builtin_amdgcn_cvt_pkrtz(fexp2(s1[2]), fexp2(s1[3]));
      vh4 vf0 = *(const vh4*)&VT[(0 * 16 + lr) * 132 + t16 * 16 + quad * 4];
      vh4 vf1 = *(const vh4*)&VT[(1 * 16 + lr) * 132 + t16 * 16 + quad * 4];
      O[0][0] = __builtin_amdgcn_mfma_f32_16x16x16f16(p0, vf0, O[0][0], 0, 0, 0);
      O[0][1] = __builtin_amdgcn_mfma_f32_16x16x16f16(p0, vf1, O[0][1], 0, 0, 0);
      O[1][0] = __builtin_amdgcn_mfma_f32_16x16x16f16(p1, vf0, O[1][0], 0, 0, 0);
      O[1][1] = __builtin_amdgcn_mfma_f32_16x16x16f16(p1, vf1, O[1][1], 0, 0, 0);
      lO[0] = __builtin_amdgcn_mfma_f32_16x16x16f16(p0, onesh, lO[0], 0, 0, 0);
      lO[1] = __builtin_amdgcn_mfma_f32_16x16x16f16(p1, onesh, lO[1], 0, 0, 0);
    }
    __builtin_amdgcn_s_setprio(0);

    if (c < 7) {                       // write prefetched chunk into the other buffer
      *(vh8*)&lds[cur ^ 1][srK * 40 + scK] = kn;
      f16* vt1 = (f16*)&lds[cur ^ 1][5120];
#pragma unroll
      for (int i = 0; i < 4; ++i) {
        vh2 pr; pr[0] = va[i]; pr[1] = vb[i];
        *(vh2*)(vt1 + (d4 + i) * 132 + kvp * 2) = pr;
      }
    }
    __syncthreads();
  }

  // epilogue: write UNNORMALIZED partial O (f16) + row-sum l (f32); LN1 normalizes
#pragma unroll
  for (int nt = 0; nt < 2; ++nt) {
#pragma unroll
    for (int r = 0; r < 4; ++r) {
      int tq = q0 + wave * 32 + nt * 16 + quad * 4 + r;    // t index 0..2047
      if (lr == 0) lf[split * 65536 + grp * 2048 + tq] = lO[nt][r];
      int row = rowbase + tq;
#pragma unroll
      for (int dt = 0; dt < 2; ++dt) {
        int col = h * 32 + dt * 16 + lr;
        Of[(size_t)split * 2097152 + (size_t)row * 256 + col] = (f16)O[nt][dt][r];
      }
    }
  }
}

// ---------------- driver ----------------
extern "C" void kernel_launch(void* const* d_in, const int* in_sizes, int n_in,
                              void* d_out, int out_size, void* d_ws, size_t ws_size,
                              hipStream_t stream) {
  (void)in_sizes; (void)n_in; (void)out_size; (void)ws_size;
  const float* x     = (const float*)d_in[0];
  const float* qkv_b = (const float*)d_in[2];
  const float* out_b = (const float*)d_in[4];
  const float* ff1_b = (const float*)d_in[6];
  const float* ff2_b = (const float*)d_in[8];
  const float* ln1_g = (const float*)d_in[9];
  const float* ln1_b = (const float*)d_in[10];
  const float* ln2_g = (const float*)d_in[11];
  const float* ln2_b = (const float*)d_in[12];

  // ws layout (bytes); total = 44,040,192
  //   [0, 8388608)          Of: attn partial O f16 [2][8192][256] (dead by ff1)
  //   [8388608, 12582912)   Xb: bf16 carried state (4 MB)
  //   [12582912, 13107200)  lf: attn partial l f32 [2][32][2048] (512 KB)
  //   [25165824, 37748736)  qkvH f16 8192x768 (12.6 MB)
  //   [20971520, 37748736)  hB bf16 ff1-out (16.8 MB) overlaps qkvH (dead by ff1)
  //   [37748736, 44040192)  transposed bf16 weights
  char* ws = (char*)d_ws;
  f16*            Of    = (f16*)(ws + 0);
  __hip_bfloat16* Xb    = (__hip_bfloat16*)(ws + 8388608);
  float*          lf    = (float*)(ws + 12582912);
  f16*            qkvH  = (f16*)(ws + 25165824);
  __hip_bfloat16* hB    = (__hip_bfloat16*)(ws + 20971520);
  u16* qkvwT = (u16*)(ws + 37748736);  // [L][768][256] bf16
  u16* outwT = (u16*)(ws + 39321600);  // [L][256][256] bf16
  u16* ff1wT = (u16*)(ws + 39845888);  // [L][1024][256] bf16
  u16* ff2wT = (u16*)(ws + 41943040);  // [L][256][1024] bf16  ends 44,040,192

  pe_kernel<<<2048, 256, 0, stream>>>(x, Xb);
  transpose_cast_all<<<3072, dim3(32, 8), 0, stream>>>(
      (const float*)d_in[1], (const float*)d_in[3], (const float*)d_in[5], (const float*)d_in[7],
      qkvwT, outwT, ff1wT, ff2wT);

  for (int l = 0; l < 4; ++l) {
    // qkv = x @ qkv_w + b -> f16 (64x128 tile, 768 blocks = 3/CU)
    gemm_qkv64<<<dim3(6, 128), 256, 0, stream>>>((const u16*)Xb, qkvwT + (size_t)l * 768 * 256,
        qkv_b + l * 768, qkvH, 8192, 768, 256);
    // attn partials (kv-split 2, 2 blocks/CU, XCD-pinned)
    attn_mfma<<<512, 512, 0, stream>>>(qkvH, Of, lf);
    // Xb = LN1((O0+O1)/l @ out_w + b + Xb)  -- combine fused into A-staging; 16-row blocks
    gemm_ln<<<512, 256, 0, stream>>>(nullptr, outwT + (size_t)l * 256 * 256,
        out_b + l * 256, Xb, ln1_g + l * 256, ln1_b + l * 256, Xb, nullptr, 256, Of, lf);
    // h = relu(Xb @ W1 + b1) -> bf16
    gemm_relu<<<dim3(8, 64), 256, 0, stream>>>((const u16*)Xb, ff1wT + (size_t)l * 1024 * 256,
        ff1_b + l * 1024, hB, 8192, 1024, 256);
    // Xb = LN2(h @ W2 + b2 + Xb); last layer also writes d_out f32; 16-row blocks
    float* lnout = (l == 3) ? (float*)d_out : nullptr;
    gemm_ln<<<512, 256, 0, stream>>>((const u16*)hB, ff2wT + (size_t)l * 256 * 1024,
        ff2_b + l * 256, Xb, ln2_g + l * 256, ln2_b + l * 256, Xb, lnout, 1024, nullptr, nullptr);
  }
}